// Round 4
// baseline (1419.446 us; speedup 1.0000x reference)
//
#include <hip/hip_runtime.h>
#include <cstdint>
#include <cstddef>

typedef __bf16 bf16;
typedef __bf16 bf16x4 __attribute__((ext_vector_type(4)));
typedef __bf16 bf16x8 __attribute__((ext_vector_type(8)));
typedef float  f32x4  __attribute__((ext_vector_type(4)));

#define LDS_CAST(p) ((__attribute__((address_space(3))) void*)(p))
#define GLB_CAST(p) ((const __attribute__((address_space(1))) void*)(p))

__device__ __forceinline__ void glds16(const void* g, void* l) {
  // 16B per lane, LDS dst = wave-uniform base + lane*16
  __builtin_amdgcn_global_load_lds(GLB_CAST(g), LDS_CAST(l), 16, 0, 0);
}

// ---------------------------------------------------------------------------
// Transpose-convert (all 6 layers, grid.z = layer): w fp32 [K,N] -> wt bf16 [N,K]
// ---------------------------------------------------------------------------
__global__ __launch_bounds__(256)
void convT_k(const float* __restrict__ w, bf16* __restrict__ wt, int K, int N)
{
  __shared__ bf16 t[64][72];
  const int tid = threadIdx.x;
  const int k0 = blockIdx.x * 64, n0 = blockIdx.y * 64;
  w  += (size_t)blockIdx.z * K * N;
  wt += (size_t)blockIdx.z * K * N;
  const int r = tid >> 4, c = (tid & 15) * 4;
#pragma unroll
  for (int p = 0; p < 4; ++p) {
    const int k = p * 16 + r;
    f32x4 v = *(const f32x4*)&w[(size_t)(k0 + k) * N + n0 + c];
    bf16x4 b = { (bf16)v[0], (bf16)v[1], (bf16)v[2], (bf16)v[3] };
    *(bf16x4*)&t[k][c] = b;
  }
  __syncthreads();
#pragma unroll
  for (int p = 0; p < 4; ++p) {
    const int n = p * 16 + r;
    bf16x4 b = { t[c + 0][n], t[c + 1][n], t[c + 2][n], t[c + 3][n] };
    *(bf16x4*)&wt[(size_t)(n0 + n) * K + k0 + c] = b;
  }
}

// ---------------------------------------------------------------------------
// GEMM, 8-wave 128x128 tile, BK=32, waves 2(row)x4(col) of 64x32 each.
// C[M,N] = A[M,K] @ Bt[N,K]^T (both bf16 row-major, glds16 staging).
// blockIdx.z = K-split slice (Kslice columns starting at z*Kslice).
// EPI 0: store bf16                       -> outB
// EPI 2: + bias, exact GELU, store bf16   -> outB
// EPI 3: atomicAdd fp32 partial           -> outF (pre-seeded with resid+bias)
// ---------------------------------------------------------------------------
template<int EPI>
__global__ __launch_bounds__(512, 4)
void gemm8_k(const bf16* __restrict__ A, const bf16* __restrict__ Bt,
             const float* __restrict__ bias, float* outF, bf16* __restrict__ outB,
             int M, int N, int K, int Kslice)
{
  __shared__ bf16 As[128 * 32];
  __shared__ bf16 Bs[128 * 32];

  const int tid  = threadIdx.x;
  const int wave = tid >> 6, lane = tid & 63;
  const int row0 = blockIdx.x * 128, col0 = blockIdx.y * 128;
  const int wr = (wave & 1) * 64, wc = (wave >> 2) * 0 + ((wave >> 1) & 3) * 32;
  const int kBase = blockIdx.z * Kslice;

  f32x4 acc[4][2] = {};

  const int sr = wave * 16 + (lane >> 2);  // staging row 0..127
  const int sk = (lane & 3) * 8;           // staging k offset

  const int nk = Kslice >> 5;
  for (int kt = 0; kt < nk; ++kt) {
    const int k0 = kBase + (kt << 5);
    glds16(&A [(size_t)(row0 + sr) * K + k0 + sk], &As[(wave * 16) * 32]);
    glds16(&Bt[(size_t)(col0 + sr) * K + k0 + sk], &Bs[(wave * 16) * 32]);
    __syncthreads();

    bf16x8 af[4], bfr[2];
#pragma unroll
    for (int t = 0; t < 4; ++t)
      af[t] = *(const bf16x8*)&As[(wr + t * 16 + (lane & 15)) * 32 + (lane >> 4) * 8];
#pragma unroll
    for (int t = 0; t < 2; ++t)
      bfr[t] = *(const bf16x8*)&Bs[(wc + t * 16 + (lane & 15)) * 32 + (lane >> 4) * 8];
#pragma unroll
    for (int i = 0; i < 4; ++i)
#pragma unroll
      for (int j = 0; j < 2; ++j)
        acc[i][j] = __builtin_amdgcn_mfma_f32_16x16x32_bf16(af[i], bfr[j], acc[i][j], 0, 0, 0);
    __syncthreads();
  }

#pragma unroll
  for (int i = 0; i < 4; ++i) {
    const int rb = row0 + wr + i * 16 + (lane >> 4) * 4;
#pragma unroll
    for (int j = 0; j < 2; ++j) {
      const int c = col0 + wc + j * 16 + (lane & 15);
      const float bv = (EPI == 2) ? bias[c] : 0.f;
#pragma unroll
      for (int r = 0; r < 4; ++r) {
        const size_t idx = (size_t)(rb + r) * N + c;
        float v = acc[i][j][r] + bv;
        if (EPI == 3) {
          atomicAdd(&outF[idx], v);
        } else {
          if (EPI == 2) v = 0.5f * v * (1.f + erff(v * 0.70710678118654752f));
          outB[idx] = (bf16)v;
        }
      }
    }
  }
}

// ---------------------------------------------------------------------------
// Seed for split-K atomic GEMMs: out = resid + bias[col]  (fp32, N=1024 rows)
// ---------------------------------------------------------------------------
__global__ __launch_bounds__(256)
void seed_k(const float* __restrict__ resid, const float* __restrict__ bias,
            float* __restrict__ out)
{
  const size_t idx = (size_t)(blockIdx.x * 256 + threadIdx.x) * 4;
  const int col = (int)(idx & 1023);
  f32x4 r = *(const f32x4*)&resid[idx];
  f32x4 b = *(const f32x4*)&bias[col];
  f32x4 o = { r[0] + b[0], r[1] + b[1], r[2] + b[2], r[3] + b[3] };
  *(f32x4*)&out[idx] = o;
}

// ---------------------------------------------------------------------------
// Attention: qkv bf16 [B*N, 3072] -> o bf16 [B*N, 1024] (col = h*64+d)
// grid (B*H=64, N/128=4), 512 threads (8 waves, 16 q-rows each).
// Full K + V^T for one head in LDS; per-wave P buffers (no inner barriers).
// ---------------------------------------------------------------------------
__global__ __launch_bounds__(512, 2)
void attn_k(const bf16* __restrict__ qkv, bf16* __restrict__ o)
{
  __shared__ bf16 Ks[512 * 72];     // [j][d], stride 72
  __shared__ bf16 Vt[64 * 520];     // [d][j], stride 520
  __shared__ bf16 Pl[8][16 * 72];   // per-wave P chunk [i][j_local], 64 cols

  const int tid = threadIdx.x, wave = tid >> 6, lane = tid & 63;
  const int b = blockIdx.x >> 4, h = blockIdx.x & 15;
  const int i0g = blockIdx.y * 128 + wave * 16;
  const bf16* base = qkv + (size_t)b * 512 * 3072;

  { // K -> LDS row-major
    const int jr = tid >> 3, c0 = (tid & 7) * 8;
#pragma unroll
    for (int p = 0; p < 8; ++p) {
      const int j = p * 64 + jr;
      *(bf16x8*)&Ks[j * 72 + c0] =
          *(const bf16x8*)&base[(size_t)j * 3072 + 1024 + h * 64 + c0];
    }
  }
  { // V -> LDS transposed
    const int jr = tid >> 4, d0 = (tid & 15) * 4;
#pragma unroll
    for (int p = 0; p < 16; ++p) {
      const int j = p * 32 + jr;
      bf16x4 v = *(const bf16x4*)&base[(size_t)j * 3072 + 2048 + h * 64 + d0];
      Vt[(d0 + 0) * 520 + j] = v[0];
      Vt[(d0 + 1) * 520 + j] = v[1];
      Vt[(d0 + 2) * 520 + j] = v[2];
      Vt[(d0 + 3) * 520 + j] = v[3];
    }
  }
  bf16x8 qf[2];
  {
    const int qr = i0g + (lane & 15);
#pragma unroll
    for (int t = 0; t < 2; ++t)
      qf[t] = *(const bf16x8*)&base[(size_t)qr * 3072 + h * 64 + t * 32 + (lane >> 4) * 8];
  }
  __syncthreads();

  // S = Q K^T : each wave 16 rows x 512 cols (32 n-tiles, 2 k-steps of 32)
  f32x4 S[32];
#pragma unroll
  for (int nt = 0; nt < 32; ++nt) {
    const bf16* kb = &Ks[(nt * 16 + (lane & 15)) * 72 + (lane >> 4) * 8];
    f32x4 c = {};
    c = __builtin_amdgcn_mfma_f32_16x16x32_bf16(qf[0], *(const bf16x8*)kb, c, 0, 0, 0);
    c = __builtin_amdgcn_mfma_f32_16x16x32_bf16(qf[1], *(const bf16x8*)(kb + 32), c, 0, 0, 0);
    S[nt] = c;
  }

  // softmax over rows (C-layout: row=(lane>>4)*4+r, col=nt*16+(lane&15))
  float mx[4] = {-1e30f, -1e30f, -1e30f, -1e30f};
#pragma unroll
  for (int nt = 0; nt < 32; ++nt)
#pragma unroll
    for (int r = 0; r < 4; ++r) {
      S[nt][r] *= 0.125f;
      mx[r] = fmaxf(mx[r], S[nt][r]);
    }
#pragma unroll
  for (int m = 1; m < 16; m <<= 1)
#pragma unroll
    for (int r = 0; r < 4; ++r) mx[r] = fmaxf(mx[r], __shfl_xor(mx[r], m));
  float sm[4] = {0.f, 0.f, 0.f, 0.f};
#pragma unroll
  for (int nt = 0; nt < 32; ++nt)
#pragma unroll
    for (int r = 0; r < 4; ++r) {
      const float e = __expf(S[nt][r] - mx[r]);
      S[nt][r] = e;
      sm[r] += e;
    }
#pragma unroll
  for (int m = 1; m < 16; m <<= 1)
#pragma unroll
    for (int r = 0; r < 4; ++r) sm[r] += __shfl_xor(sm[r], m);
  float inv[4];
#pragma unroll
  for (int r = 0; r < 4; ++r) inv[r] = 1.f / sm[r];

  // O = P V: P roundtrips per-wave LDS (C-layout -> A-layout), 8 chunks of 64
  f32x4 O[4] = {};
  for (int cch = 0; cch < 8; ++cch) {
#pragma unroll
    for (int t = 0; t < 4; ++t) {
      const int nt = cch * 4 + t;
#pragma unroll
      for (int r = 0; r < 4; ++r)
        Pl[wave][((lane >> 4) * 4 + r) * 72 + t * 16 + (lane & 15)] = (bf16)S[nt][r];
    }
#pragma unroll
    for (int ktile = 0; ktile < 2; ++ktile) {
      bf16x8 pf = *(const bf16x8*)&Pl[wave][(lane & 15) * 72 + ktile * 32 + (lane >> 4) * 8];
#pragma unroll
      for (int dt = 0; dt < 4; ++dt) {
        const bf16* vb = &Vt[(dt * 16 + (lane & 15)) * 520 + cch * 64 + ktile * 32 + (lane >> 4) * 8];
        O[dt] = __builtin_amdgcn_mfma_f32_16x16x32_bf16(pf, *(const bf16x8*)vb, O[dt], 0, 0, 0);
      }
    }
  }

#pragma unroll
  for (int dt = 0; dt < 4; ++dt)
#pragma unroll
    for (int r = 0; r < 4; ++r) {
      const int i = (lane >> 4) * 4 + r;
      const int d = dt * 16 + (lane & 15);
      o[(size_t)(b * 512 + i0g + i) * 1024 + h * 64 + d] = (bf16)(O[dt][r] * inv[r]);
    }
}

// ---------------------------------------------------------------------------
// LayerNorm: x fp32 [rows,1024], fp32 scale/bias -> bf16 out
// ---------------------------------------------------------------------------
__global__ __launch_bounds__(256)
void ln_k(const float* __restrict__ x, const float* __restrict__ sc,
          const float* __restrict__ bi, bf16* __restrict__ out)
{
  const int row = blockIdx.x, tid = threadIdx.x;
  f32x4 a = *(const f32x4*)&x[(size_t)row * 1024 + tid * 4];
  float s  = a[0] + a[1] + a[2] + a[3];
  float s2 = a[0]*a[0] + a[1]*a[1] + a[2]*a[2] + a[3]*a[3];
#pragma unroll
  for (int m = 32; m >= 1; m >>= 1) {
    s  += __shfl_xor(s, m);
    s2 += __shfl_xor(s2, m);
  }
  __shared__ float red[8];
  if ((tid & 63) == 0) { red[tid >> 6] = s; red[4 + (tid >> 6)] = s2; }
  __syncthreads();
  s  = red[0] + red[1] + red[2] + red[3];
  s2 = red[4] + red[5] + red[6] + red[7];
  const float mean = s * (1.f / 1024.f);
  const float var  = s2 * (1.f / 1024.f) - mean * mean;
  const float rs   = rsqrtf(var + 1e-5f);
  bf16x4 ov;
#pragma unroll
  for (int i = 0; i < 4; ++i) {
    const int c = tid * 4 + i;
    ov[i] = (bf16)((a[i] - mean) * rs * sc[c] + bi[c]);
  }
  *(bf16x4*)&out[(size_t)row * 1024 + tid * 4] = ov;
}

// ---------------------------------------------------------------------------
extern "C" void kernel_launch(void* const* d_in, const int* in_sizes, int n_in,
                              void* d_out, int out_size, void* d_ws, size_t ws_size,
                              hipStream_t stream)
{
  const float* x_in = (const float*)d_in[0];
  const float* ln1s = (const float*)d_in[1];
  const float* ln1b = (const float*)d_in[2];
  const float* wqkv = (const float*)d_in[3];
  const float* wout = (const float*)d_in[4];
  const float* bout = (const float*)d_in[5];
  const float* ln2s = (const float*)d_in[6];
  const float* ln2b = (const float*)d_in[7];
  const float* w1   = (const float*)d_in[8];
  const float* b1   = (const float*)d_in[9];
  const float* w2   = (const float*)d_in[10];
  const float* b2   = (const float*)d_in[11];

  char* ws = (char*)d_ws;
  const size_t MB = 1 << 20;
  float* xf   = (float*)(ws);              // 8 MiB fp32 residual stream
  bf16* act   = (bf16*)(ws + 8   * MB);    // 4 MiB: ln out / attn out
  bf16* qg    = (bf16*)(ws + 12  * MB);    // 16 MiB: qkv (12) then gelu (16)
  bf16* qkvT  = (bf16*)(ws + 28  * MB);    // 36 MiB [6][3072,1024]
  bf16* woutT = (bf16*)(ws + 64  * MB);    // 12 MiB [6][1024,1024]
  bf16* w1T   = (bf16*)(ws + 76  * MB);    // 48 MiB [6][4096,1024]
  bf16* w2T   = (bf16*)(ws + 124 * MB);    // 48 MiB [6][1024,4096] (end 172 MiB)

  // transpose-convert all layers' weights to bf16 [N,K]
  convT_k<<<dim3(16, 48, 6), 256, 0, stream>>>(wqkv, qkvT, 1024, 3072);
  convT_k<<<dim3(16, 16, 6), 256, 0, stream>>>(wout, woutT, 1024, 1024);
  convT_k<<<dim3(16, 64, 6), 256, 0, stream>>>(w1, w1T, 1024, 4096);
  convT_k<<<dim3(64, 16, 6), 256, 0, stream>>>(w2, w2T, 4096, 1024);

  for (int l = 0; l < 6; ++l) {
    const float* xres = (l == 0) ? x_in : xf;  // residual-stream input
    ln_k<<<2048, 256, 0, stream>>>(xres, ln1s + l * 1024, ln1b + l * 1024, act);
    gemm8_k<0><<<dim3(16, 24, 1), 512, 0, stream>>>(
        act, qkvT + (size_t)l * 3072 * 1024, nullptr, nullptr, qg,
        2048, 3072, 1024, 1024);
    attn_k<<<dim3(64, 4), 512, 0, stream>>>(qg, act);
    // wout: split-K=4, atomic into xf seeded with xres + bout
    seed_k<<<2048, 256, 0, stream>>>(xres, bout + l * 1024, xf);
    gemm8_k<3><<<dim3(16, 8, 4), 512, 0, stream>>>(
        act, woutT + (size_t)l * 1024 * 1024, nullptr, xf, nullptr,
        2048, 1024, 1024, 256);
    ln_k<<<2048, 256, 0, stream>>>(xf, ln2s + l * 1024, ln2b + l * 1024, act);
    gemm8_k<2><<<dim3(16, 32, 1), 512, 0, stream>>>(
        act, w1T + (size_t)l * 4096 * 1024, b1 + l * 4096, nullptr, qg,
        2048, 4096, 1024, 1024);
    // ff2: split-K=4, atomic into out seeded with xf + b2
    float* outp = (l == 5) ? (float*)d_out : xf;
    seed_k<<<2048, 256, 0, stream>>>(xf, b2 + l * 1024, outp);
    gemm8_k<3><<<dim3(16, 8, 4), 512, 0, stream>>>(
        qg, w2T + (size_t)l * 1024 * 4096, nullptr, outp, nullptr,
        2048, 1024, 4096, 1024);
  }
}

// Round 5
// 1266.242 us; speedup vs baseline: 1.1210x; 1.1210x over previous
//
#include <hip/hip_runtime.h>
#include <cstdint>
#include <cstddef>

typedef __bf16 bf16;
typedef __bf16 bf16x4 __attribute__((ext_vector_type(4)));
typedef __bf16 bf16x8 __attribute__((ext_vector_type(8)));
typedef float  f32x4  __attribute__((ext_vector_type(4)));

#define LDS_CAST(p) ((__attribute__((address_space(3))) void*)(p))
#define GLB_CAST(p) ((const __attribute__((address_space(1))) void*)(p))

__device__ __forceinline__ void glds16(const void* g, void* l) {
  // 16B per lane, LDS dst = wave-uniform base + lane*16
  __builtin_amdgcn_global_load_lds(GLB_CAST(g), LDS_CAST(l), 16, 0, 0);
}

// ---------------------------------------------------------------------------
// Transpose-convert (all 6 layers, grid.z = layer): w fp32 [K,N] -> wt bf16 [N,K]
// ---------------------------------------------------------------------------
__global__ __launch_bounds__(256)
void convT_k(const float* __restrict__ w, bf16* __restrict__ wt, int K, int N)
{
  __shared__ bf16 t[64][72];
  const int tid = threadIdx.x;
  const int k0 = blockIdx.x * 64, n0 = blockIdx.y * 64;
  w  += (size_t)blockIdx.z * K * N;
  wt += (size_t)blockIdx.z * K * N;
  const int r = tid >> 4, c = (tid & 15) * 4;
#pragma unroll
  for (int p = 0; p < 4; ++p) {
    const int k = p * 16 + r;
    f32x4 v = *(const f32x4*)&w[(size_t)(k0 + k) * N + n0 + c];
    bf16x4 b = { (bf16)v[0], (bf16)v[1], (bf16)v[2], (bf16)v[3] };
    *(bf16x4*)&t[k][c] = b;
  }
  __syncthreads();
#pragma unroll
  for (int p = 0; p < 4; ++p) {
    const int n = p * 16 + r;
    bf16x4 b = { t[c + 0][n], t[c + 1][n], t[c + 2][n], t[c + 3][n] };
    *(bf16x4*)&wt[(size_t)(n0 + n) * K + k0 + c] = b;
  }
}

// ---------------------------------------------------------------------------
// GEMM (m97 structure): C = A[M,K] @ Bt[N,K]^T, both bf16 row-major, glds16
// staging. 128x128 tile, BK=32, 4 waves as 2x2 of 64x64.
// EPI 0: store bf16               EPI 2: +bias, exact GELU, store bf16
// ---------------------------------------------------------------------------
template<int EPI>
__global__ __launch_bounds__(256)
void gemm128_k(const bf16* __restrict__ A, const bf16* __restrict__ Bt,
               const float* __restrict__ bias, bf16* __restrict__ outB,
               int M, int N, int K)
{
  __shared__ bf16 As[128 * 32];
  __shared__ bf16 Bs[128 * 32];

  const int tid  = threadIdx.x;
  const int wave = tid >> 6, lane = tid & 63;
  const int row0 = blockIdx.x * 128, col0 = blockIdx.y * 128;
  const int wm = (wave & 1) * 64, wn = (wave >> 1) * 64;

  f32x4 acc[4][4] = {};

  const int sr = wave * 32 + (lane >> 2);  // staging row within tile
  const int sk = (lane & 3) * 8;           // staging k offset

  const int nk = K >> 5;
  for (int kt = 0; kt < nk; ++kt) {
    const int k0 = kt << 5;
    glds16(&A [(size_t)(row0 + sr)      * K + k0 + sk], &As[(wave * 32)      * 32]);
    glds16(&A [(size_t)(row0 + sr + 16) * K + k0 + sk], &As[(wave * 32 + 16) * 32]);
    glds16(&Bt[(size_t)(col0 + sr)      * K + k0 + sk], &Bs[(wave * 32)      * 32]);
    glds16(&Bt[(size_t)(col0 + sr + 16) * K + k0 + sk], &Bs[(wave * 32 + 16) * 32]);
    __syncthreads();

    bf16x8 af[4], bfr[4];
#pragma unroll
    for (int t = 0; t < 4; ++t) {
      af[t]  = *(const bf16x8*)&As[(wm + t * 16 + (lane & 15)) * 32 + (lane >> 4) * 8];
      bfr[t] = *(const bf16x8*)&Bs[(wn + t * 16 + (lane & 15)) * 32 + (lane >> 4) * 8];
    }
#pragma unroll
    for (int i = 0; i < 4; ++i)
#pragma unroll
      for (int j = 0; j < 4; ++j)
        acc[i][j] = __builtin_amdgcn_mfma_f32_16x16x32_bf16(af[i], bfr[j], acc[i][j], 0, 0, 0);
    __syncthreads();
  }

#pragma unroll
  for (int i = 0; i < 4; ++i) {
    const int rb = row0 + wm + i * 16 + (lane >> 4) * 4;
#pragma unroll
    for (int j = 0; j < 4; ++j) {
      const int c = col0 + wn + j * 16 + (lane & 15);
      const float bv = (EPI == 2) ? bias[c] : 0.f;
#pragma unroll
      for (int r = 0; r < 4; ++r) {
        float v = acc[i][j][r] + bv;
        if (EPI == 2) v = 0.5f * v * (1.f + erff(v * 0.70710678118654752f));
        outB[(size_t)(rb + r) * N + c] = (bf16)v;
      }
    }
  }
}

// ---------------------------------------------------------------------------
// N=1024 GEMMs (wout, ff2): 64x64 tile, 8 waves, intra-block split-K x2.
// Waves 0-3 accumulate K[0,K/2), waves 4-7 K[K/2,K); group-1 acc goes through
// LDS (reused staging space) and group-0 stores: out = a0+a1 + bias + resid
// (fp32; resid may alias out). Grid 32x16 = 512 blocks -> 16 waves/CU.
// ---------------------------------------------------------------------------
__global__ __launch_bounds__(512, 4)
void gemm64s_k(const bf16* __restrict__ A, const bf16* __restrict__ Bt,
               const float* __restrict__ bias, const float* resid,
               float* outF, int M, int N, int K)
{
  __shared__ bf16 As[2][64 * 32];   // per K-group staging (8 KB)
  __shared__ bf16 Bs[2][64 * 32];   // (8 KB)

  const int tid  = threadIdx.x;
  const int wave = tid >> 6, lane = tid & 63;
  const int g = wave >> 2, w4 = wave & 3;
  const int row0 = blockIdx.x * 64, col0 = blockIdx.y * 64;
  const int wm = (w4 & 1) * 32, wn = (w4 >> 1) * 32;
  const int kBase = g * (K >> 1);

  f32x4 acc[2][2] = {};

  const int sr = w4 * 16 + (lane >> 2);
  const int sk = (lane & 3) * 8;

  const int nk = K >> 6;            // (K/2)/32 tiles per group
  for (int kt = 0; kt < nk; ++kt) {
    const int k0 = kBase + (kt << 5);
    glds16(&A [(size_t)(row0 + sr) * K + k0 + sk], &As[g][(w4 * 16) * 32]);
    glds16(&Bt[(size_t)(col0 + sr) * K + k0 + sk], &Bs[g][(w4 * 16) * 32]);
    __syncthreads();

    bf16x8 af[2], bfr[2];
#pragma unroll
    for (int t = 0; t < 2; ++t) {
      af[t]  = *(const bf16x8*)&As[g][(wm + t * 16 + (lane & 15)) * 32 + (lane >> 4) * 8];
      bfr[t] = *(const bf16x8*)&Bs[g][(wn + t * 16 + (lane & 15)) * 32 + (lane >> 4) * 8];
    }
#pragma unroll
    for (int i = 0; i < 2; ++i)
#pragma unroll
      for (int j = 0; j < 2; ++j)
        acc[i][j] = __builtin_amdgcn_mfma_f32_16x16x32_bf16(af[i], bfr[j], acc[i][j], 0, 0, 0);
    __syncthreads();
  }

  // cross-group reduce: group 1 -> LDS (16 KB scratch reuses As+Bs), group 0 stores
  float* red = (float*)&As[0][0];   // 64*64 fp32 = 16 KB
  if (g == 1) {
#pragma unroll
    for (int i = 0; i < 2; ++i)
#pragma unroll
      for (int j = 0; j < 2; ++j)
#pragma unroll
        for (int r = 0; r < 4; ++r)
          red[(wm + i * 16 + (lane >> 4) * 4 + r) * 64 + wn + j * 16 + (lane & 15)] =
              acc[i][j][r];
  }
  __syncthreads();
  if (g == 0) {
#pragma unroll
    for (int i = 0; i < 2; ++i) {
      const int rl = wm + i * 16 + (lane >> 4) * 4;
#pragma unroll
      for (int j = 0; j < 2; ++j) {
        const int cl = wn + j * 16 + (lane & 15);
        const int c = col0 + cl;
        const float bv = bias[c];
#pragma unroll
        for (int r = 0; r < 4; ++r) {
          const size_t idx = (size_t)(row0 + rl + r) * N + c;
          outF[idx] = acc[i][j][r] + red[(rl + r) * 64 + cl] + bv + resid[idx];
        }
      }
    }
  }
}

// ---------------------------------------------------------------------------
// Attention: qkv bf16 [B*N, 3072] -> o bf16 [B*N, 1024] (col = h*64+d)
// grid (B*H=64, N/128=4), 512 threads (8 waves, 16 q-rows each).
// Full K + V^T for one head in LDS; per-wave P buffers (no inner barriers).
// ---------------------------------------------------------------------------
__global__ __launch_bounds__(512, 2)
void attn_k(const bf16* __restrict__ qkv, bf16* __restrict__ o)
{
  __shared__ bf16 Ks[512 * 72];     // [j][d], stride 72
  __shared__ bf16 Vt[64 * 520];     // [d][j], stride 520
  __shared__ bf16 Pl[8][16 * 72];   // per-wave P chunk [i][j_local], 64 cols

  const int tid = threadIdx.x, wave = tid >> 6, lane = tid & 63;
  const int b = blockIdx.x >> 4, h = blockIdx.x & 15;
  const int i0g = blockIdx.y * 128 + wave * 16;
  const bf16* base = qkv + (size_t)b * 512 * 3072;

  { // K -> LDS row-major
    const int jr = tid >> 3, c0 = (tid & 7) * 8;
#pragma unroll
    for (int p = 0; p < 8; ++p) {
      const int j = p * 64 + jr;
      *(bf16x8*)&Ks[j * 72 + c0] =
          *(const bf16x8*)&base[(size_t)j * 3072 + 1024 + h * 64 + c0];
    }
  }
  { // V -> LDS transposed
    const int jr = tid >> 4, d0 = (tid & 15) * 4;
#pragma unroll
    for (int p = 0; p < 16; ++p) {
      const int j = p * 32 + jr;
      bf16x4 v = *(const bf16x4*)&base[(size_t)j * 3072 + 2048 + h * 64 + d0];
      Vt[(d0 + 0) * 520 + j] = v[0];
      Vt[(d0 + 1) * 520 + j] = v[1];
      Vt[(d0 + 2) * 520 + j] = v[2];
      Vt[(d0 + 3) * 520 + j] = v[3];
    }
  }
  bf16x8 qf[2];
  {
    const int qr = i0g + (lane & 15);
#pragma unroll
    for (int t = 0; t < 2; ++t)
      qf[t] = *(const bf16x8*)&base[(size_t)qr * 3072 + h * 64 + t * 32 + (lane >> 4) * 8];
  }
  __syncthreads();

  // S = Q K^T : each wave 16 rows x 512 cols (32 n-tiles, 2 k-steps of 32)
  f32x4 S[32];
#pragma unroll
  for (int nt = 0; nt < 32; ++nt) {
    const bf16* kb = &Ks[(nt * 16 + (lane & 15)) * 72 + (lane >> 4) * 8];
    f32x4 c = {};
    c = __builtin_amdgcn_mfma_f32_16x16x32_bf16(qf[0], *(const bf16x8*)kb, c, 0, 0, 0);
    c = __builtin_amdgcn_mfma_f32_16x16x32_bf16(qf[1], *(const bf16x8*)(kb + 32), c, 0, 0, 0);
    S[nt] = c;
  }

  // softmax over rows (C-layout: row=(lane>>4)*4+r, col=nt*16+(lane&15))
  float mx[4] = {-1e30f, -1e30f, -1e30f, -1e30f};
#pragma unroll
  for (int nt = 0; nt < 32; ++nt)
#pragma unroll
    for (int r = 0; r < 4; ++r) {
      S[nt][r] *= 0.125f;
      mx[r] = fmaxf(mx[r], S[nt][r]);
    }
#pragma unroll
  for (int m = 1; m < 16; m <<= 1)
#pragma unroll
    for (int r = 0; r < 4; ++r) mx[r] = fmaxf(mx[r], __shfl_xor(mx[r], m));
  float sm[4] = {0.f, 0.f, 0.f, 0.f};
#pragma unroll
  for (int nt = 0; nt < 32; ++nt)
#pragma unroll
    for (int r = 0; r < 4; ++r) {
      const float e = __expf(S[nt][r] - mx[r]);
      S[nt][r] = e;
      sm[r] += e;
    }
#pragma unroll
  for (int m = 1; m < 16; m <<= 1)
#pragma unroll
    for (int r = 0; r < 4; ++r) sm[r] += __shfl_xor(sm[r], m);
  float inv[4];
#pragma unroll
  for (int r = 0; r < 4; ++r) inv[r] = 1.f / sm[r];

  // O = P V: P roundtrips per-wave LDS (C-layout -> A-layout), 8 chunks of 64
  f32x4 O[4] = {};
  for (int cch = 0; cch < 8; ++cch) {
#pragma unroll
    for (int t = 0; t < 4; ++t) {
      const int nt = cch * 4 + t;
#pragma unroll
      for (int r = 0; r < 4; ++r)
        Pl[wave][((lane >> 4) * 4 + r) * 72 + t * 16 + (lane & 15)] = (bf16)S[nt][r];
    }
#pragma unroll
    for (int ktile = 0; ktile < 2; ++ktile) {
      bf16x8 pf = *(const bf16x8*)&Pl[wave][(lane & 15) * 72 + ktile * 32 + (lane >> 4) * 8];
#pragma unroll
      for (int dt = 0; dt < 4; ++dt) {
        const bf16* vb = &Vt[(dt * 16 + (lane & 15)) * 520 + cch * 64 + ktile * 32 + (lane >> 4) * 8];
        O[dt] = __builtin_amdgcn_mfma_f32_16x16x32_bf16(pf, *(const bf16x8*)vb, O[dt], 0, 0, 0);
      }
    }
  }

#pragma unroll
  for (int dt = 0; dt < 4; ++dt)
#pragma unroll
    for (int r = 0; r < 4; ++r) {
      const int i = (lane >> 4) * 4 + r;
      const int d = dt * 16 + (lane & 15);
      o[(size_t)(b * 512 + i0g + i) * 1024 + h * 64 + d] = (bf16)(O[dt][r] * inv[r]);
    }
}

// ---------------------------------------------------------------------------
// LayerNorm: x fp32 [rows,1024], fp32 scale/bias -> bf16 out
// ---------------------------------------------------------------------------
__global__ __launch_bounds__(256)
void ln_k(const float* __restrict__ x, const float* __restrict__ sc,
          const float* __restrict__ bi, bf16* __restrict__ out)
{
  const int row = blockIdx.x, tid = threadIdx.x;
  f32x4 a = *(const f32x4*)&x[(size_t)row * 1024 + tid * 4];
  float s  = a[0] + a[1] + a[2] + a[3];
  float s2 = a[0]*a[0] + a[1]*a[1] + a[2]*a[2] + a[3]*a[3];
#pragma unroll
  for (int m = 32; m >= 1; m >>= 1) {
    s  += __shfl_xor(s, m);
    s2 += __shfl_xor(s2, m);
  }
  __shared__ float red[8];
  if ((tid & 63) == 0) { red[tid >> 6] = s; red[4 + (tid >> 6)] = s2; }
  __syncthreads();
  s  = red[0] + red[1] + red[2] + red[3];
  s2 = red[4] + red[5] + red[6] + red[7];
  const float mean = s * (1.f / 1024.f);
  const float var  = s2 * (1.f / 1024.f) - mean * mean;
  const float rs   = rsqrtf(var + 1e-5f);
  bf16x4 ov;
#pragma unroll
  for (int i = 0; i < 4; ++i) {
    const int c = tid * 4 + i;
    ov[i] = (bf16)((a[i] - mean) * rs * sc[c] + bi[c]);
  }
  *(bf16x4*)&out[(size_t)row * 1024 + tid * 4] = ov;
}

// ---------------------------------------------------------------------------
extern "C" void kernel_launch(void* const* d_in, const int* in_sizes, int n_in,
                              void* d_out, int out_size, void* d_ws, size_t ws_size,
                              hipStream_t stream)
{
  const float* x_in = (const float*)d_in[0];
  const float* ln1s = (const float*)d_in[1];
  const float* ln1b = (const float*)d_in[2];
  const float* wqkv = (const float*)d_in[3];
  const float* wout = (const float*)d_in[4];
  const float* bout = (const float*)d_in[5];
  const float* ln2s = (const float*)d_in[6];
  const float* ln2b = (const float*)d_in[7];
  const float* w1   = (const float*)d_in[8];
  const float* b1   = (const float*)d_in[9];
  const float* w2   = (const float*)d_in[10];
  const float* b2   = (const float*)d_in[11];

  char* ws = (char*)d_ws;
  const size_t MB = 1 << 20;
  float* xf   = (float*)(ws);              // 8 MiB fp32 residual stream
  bf16* act   = (bf16*)(ws + 8   * MB);    // 4 MiB: ln out / attn out
  bf16* qg    = (bf16*)(ws + 12  * MB);    // 16 MiB: qkv (12) then gelu (16)
  bf16* qkvT  = (bf16*)(ws + 28  * MB);    // 36 MiB [6][3072,1024]
  bf16* woutT = (bf16*)(ws + 64  * MB);    // 12 MiB [6][1024,1024]
  bf16* w1T   = (bf16*)(ws + 76  * MB);    // 48 MiB [6][4096,1024]
  bf16* w2T   = (bf16*)(ws + 124 * MB);    // 48 MiB [6][1024,4096] (end 172 MiB)

  // transpose-convert all layers' weights to bf16 [N,K]
  convT_k<<<dim3(16, 48, 6), 256, 0, stream>>>(wqkv, qkvT, 1024, 3072);
  convT_k<<<dim3(16, 16, 6), 256, 0, stream>>>(wout, woutT, 1024, 1024);
  convT_k<<<dim3(16, 64, 6), 256, 0, stream>>>(w1, w1T, 1024, 4096);
  convT_k<<<dim3(64, 16, 6), 256, 0, stream>>>(w2, w2T, 4096, 1024);

  for (int l = 0; l < 6; ++l) {
    const float* xres = (l == 0) ? x_in : xf;  // residual-stream input
    ln_k<<<2048, 256, 0, stream>>>(xres, ln1s + l * 1024, ln1b + l * 1024, act);
    gemm128_k<0><<<dim3(16, 24), 256, 0, stream>>>(
        act, qkvT + (size_t)l * 3072 * 1024, nullptr, qg, 2048, 3072, 1024);
    attn_k<<<dim3(64, 4), 512, 0, stream>>>(qg, act);
    gemm64s_k<<<dim3(32, 16), 512, 0, stream>>>(
        act, woutT + (size_t)l * 1024 * 1024, bout + l * 1024, xres, xf,
        2048, 1024, 1024);
    ln_k<<<2048, 256, 0, stream>>>(xf, ln2s + l * 1024, ln2b + l * 1024, act);
    gemm128_k<2><<<dim3(16, 32), 256, 0, stream>>>(
        act, w1T + (size_t)l * 4096 * 1024, b1 + l * 4096, qg, 2048, 4096, 1024);
    float* outp = (l == 5) ? (float*)d_out : xf;
    gemm64s_k<<<dim3(32, 16), 512, 0, stream>>>(
        qg, w2T + (size_t)l * 1024 * 4096, b2 + l * 1024, xf, outp,
        2048, 1024, 4096);
  }
}